// Round 3
// baseline (3688.079 us; speedup 1.0000x reference)
//
#include <hip/hip_runtime.h>

#define NB 256
#define NT 512
#define Bz 8
#define T1z 13
#define Tz 12
#define Vz 20000
#define Ez 512
#define Dz 512
#define Kz 512
#define Cz 2048
#define Pz 64

__device__ __forceinline__ float waveReduce(float v) {
    #pragma unroll
    for (int off = 32; off > 0; off >>= 1) v += __shfl_xor(v, off);
    return v;
}

__device__ __forceinline__ float sigf(float x) {
    return 1.0f / (1.0f + expf(-x));
}

__device__ __forceinline__ void gbar(unsigned* cnt, unsigned& phase) {
    __syncthreads();
    phase += NB;
    if (threadIdx.x == 0) {
        __threadfence();
        __hip_atomic_fetch_add(cnt, 1u, __ATOMIC_RELAXED, __HIP_MEMORY_SCOPE_AGENT);
        while (__hip_atomic_load(cnt, __ATOMIC_RELAXED, __HIP_MEMORY_SCOPE_AGENT) < phase)
            __builtin_amdgcn_s_sleep(1);
        __threadfence();
    }
    __syncthreads();
}

// wave computes nv preds rows starting at v0 for timestep tt
__device__ __forceinline__ void predsWave(const float* __restrict__ h,
                                          const float* __restrict__ W_fc,
                                          const float* __restrict__ b_fc,
                                          float* __restrict__ out,
                                          int tt, int v0, int nv, int lane) {
    int bb = lane >> 3, d8 = lane & 7;
    const float4* hv = (const float4*)(h + bb * Dz);
    float4 hreg[16];
    #pragma unroll
    for (int i = 0; i < 16; i++) hreg[i] = hv[i * 8 + d8];
    for (int j = 0; j < nv; j++) {
        int v = v0 + j;
        if (v < Vz) {
            const float4* Wv = (const float4*)(W_fc + (size_t)v * Dz);
            float acc = 0.0f;
            #pragma unroll
            for (int i = 0; i < 16; i++) {
                float4 w = Wv[i * 8 + d8];
                acc = fmaf(hreg[i].x, w.x, acc);
                acc = fmaf(hreg[i].y, w.y, acc);
                acc = fmaf(hreg[i].z, w.z, acc);
                acc = fmaf(hreg[i].w, w.w, acc);
            }
            acc += __shfl_xor(acc, 1);
            acc += __shfl_xor(acc, 2);
            acc += __shfl_xor(acc, 4);
            if (d8 == 0) out[((size_t)bb * Tz + tt) * Vz + v] = acc + b_fc[v];
        }
    }
}

__global__ void k_zero(unsigned* cnt) { if (threadIdx.x == 0) *cnt = 0u; }

__global__ __launch_bounds__(NT, 2) void k_main(
    const float* __restrict__ enc, const int* __restrict__ caps,
    const int* __restrict__ caplen,
    const float* __restrict__ W_c, const float* __restrict__ W_hc,
    const float* __restrict__ W_i_hat, const float* __restrict__ b_c,
    const float* __restrict__ W_s, const float* __restrict__ W_hs,
    const float* __restrict__ W_i, const float* __restrict__ b_s,
    const float* __restrict__ emb, const float* __restrict__ W_ih,
    const float* __restrict__ W_hh, const float* __restrict__ b_ih,
    const float* __restrict__ b_hh, const float* __restrict__ W_init_h,
    const float* __restrict__ b_init_h, const float* __restrict__ W_init_c,
    const float* __restrict__ b_init_c, const float* __restrict__ W_fc,
    const float* __restrict__ b_fc,
    float* __restrict__ out, float* __restrict__ ws, unsigned* cnt)
{
    const int blk = blockIdx.x, tid = threadIdx.x;
    const int wave = tid >> 6, lane = tid & 63;
    const int gw = blk * 8 + wave;            // 0..2047
    unsigned phase = 0;

    float* vmean = ws;                        // 16384
    float* h     = ws + 16384;                // 4096
    float* c     = ws + 20480;                // 4096
    float* qc    = ws + 24576;                // 4096
    float* qs    = ws + 28672;                // 4096
    float* beta  = ws + 32768;                // 16384
    float* alpha = ws + 49152;                // 512
    float* xcat  = ws + 49664;                // 24576
    float* spart = ws + 74240;                // 8*8*64*512 = 2097152

    __shared__ __align__(16) float ldsA[64 * 64];
    __shared__ __align__(16) float ldsB[2 * 64 * 64];
    __shared__ float sred[128];

    // ---------------- stage 0a: vmean + output tail ----------------
    #pragma unroll
    for (int r = 0; r < 8; r++) {
        int row = gw * 8 + r;                 // (b*C + c)
        float v = enc[row * 64 + lane];
        v = waveReduce(v);
        if (lane == 0) vmean[row] = v * (1.0f / 64.0f);
    }
    if (blk == 0) {
        const int base = Bz * Tz * Vz;
        const int nCap = Bz * T1z, nLen = Bz, nAlp = Bz * Tz * Pz;
        for (int idx = tid; idx < nCap + nLen + nAlp + Bz; idx += NT) {
            float val;
            if (idx < nCap) val = (float)caps[idx];
            else if (idx < nCap + nLen) val = (float)(caplen[idx - nCap] - 1);
            else if (idx < nCap + nLen + nAlp) val = 0.0f;
            else val = (float)(idx - (nCap + nLen + nAlp));
            out[base + idx] = val;
        }
    }
    gbar(cnt, phase);

    // ---------------- stage 0b: h0, c0 ----------------
    {
        const float4* vm4 = (const float4*)vmean;
        #pragma unroll
        for (int r = 0; r < 4; r++) {
            int id = gw * 4 + r;              // 0..8191
            int which = id >> 12;
            int b = (id >> 9) & 7;
            int d = id & 511;
            const float* W = which ? W_init_c : W_init_h;
            const float4* W4 = (const float4*)(W + (size_t)d * Cz);
            float acc = 0.0f;
            #pragma unroll
            for (int i = 0; i < 8; i++) {
                float4 wv = W4[i * 64 + lane];
                float4 xv = vm4[b * (Cz / 4) + i * 64 + lane];
                acc = fmaf(wv.x, xv.x, acc); acc = fmaf(wv.y, xv.y, acc);
                acc = fmaf(wv.z, xv.z, acc); acc = fmaf(wv.w, xv.w, acc);
            }
            acc = waveReduce(acc);
            if (lane == 0) {
                if (which) c[b * Dz + d] = acc + b_init_c[d];
                else       h[b * Dz + d] = acc + b_init_h[d];
            }
        }
    }
    gbar(cnt, phase);

    for (int t = 0; t < Tz; t++) {
        // ---------- stage 1: qc/qs (blocks 0..15) | preds(t-1) (rest) ----------
        if (blk < 16) {
            int which = blk >> 3, b = blk & 7;
            const float* W = which ? W_hs : W_hc;
            const float* bias = which ? b_s : b_c;
            const float* hb = h + b * Dz;
            int k = tid;
            float a0 = bias[k], a1 = 0.f, a2 = 0.f, a3 = 0.f;
            for (int d = 0; d < Dz; d += 4) {
                a0 = fmaf(hb[d],     W[(d)     * Kz + k], a0);
                a1 = fmaf(hb[d + 1], W[(d + 1) * Kz + k], a1);
                a2 = fmaf(hb[d + 2], W[(d + 2) * Kz + k], a2);
                a3 = fmaf(hb[d + 3], W[(d + 3) * Kz + k], a3);
            }
            (which ? qs : qc)[b * Kz + k] = (a0 + a1) + (a2 + a3);
        } else if (t > 0) {
            int gw2 = (blk - 16) * 8 + wave;  // 0..1919
            predsWave(h, W_fc, b_fc, out, t - 1, gw2 * 11, 11, lane);
        }
        gbar(cnt, phase);

        // ---------- stage 2: channel attention + batch softmax → beta ----------
        {
            int cg = blk;                     // 8 channels per block
            int b = wave;
            int c8 = lane >> 3, k8 = lane & 7;
            int cc = cg * 8 + c8;
            float v = vmean[b * Cz + cc];
            float acc = 0.0f;
            #pragma unroll 8
            for (int i = 0; i < 64; i++) {
                int k = i * 8 + k8;
                acc += tanhf(fmaf(v, W_c[k], qc[b * Kz + k])) * W_i_hat[k];
            }
            acc += __shfl_xor(acc, 1);
            acc += __shfl_xor(acc, 2);
            acc += __shfl_xor(acc, 4);
            if (k8 == 0) sred[c8 * 8 + b] = acc;
            __syncthreads();
            if (tid < 64) {
                int c8_ = tid >> 3, b_ = tid & 7;
                float m = -1e30f;
                #pragma unroll
                for (int j = 0; j < 8; j++) m = fmaxf(m, sred[c8_ * 8 + j]);
                float s = 0.0f;
                #pragma unroll
                for (int j = 0; j < 8; j++) s += expf(sred[c8_ * 8 + j] - m);
                beta[b_ * Cz + cg * 8 + c8_] = expf(sred[c8_ * 8 + b_] - m) / s;
            }
        }
        gbar(cnt, phase);

        // ---------- stage 3: einsum partials spart[cs][b][p][k] ----------
        {
            int cs = blk >> 5;                // 0..7 (256-channel slice)
            int ktp = (blk >> 3) & 3;         // 0..3 (pair of 64-k tiles)
            int b = blk & 7;
            int g = tid >> 8;                 // which ktile of the pair
            int tl = tid & 255;
            int kq = tl & 15, pq = tl >> 4;
            float acc[4][4] = {};
            for (int chunk = 0; chunk < 4; chunk++) {
                int c0 = cs * 256 + chunk * 64;
                __syncthreads();
                #pragma unroll
                for (int i = 0; i < 8; i++) {
                    int idx = tid + i * 512;
                    int cl = idx >> 6, p = idx & 63;
                    ldsA[idx] = enc[(size_t)(b * Cz + c0 + cl) * 64 + p]
                              * beta[b * Cz + c0 + cl];
                }
                #pragma unroll
                for (int i = 0; i < 16; i++) {
                    int idx = tid + i * 512;
                    int t2 = idx >> 12, rem = idx & 4095;
                    int cl = rem >> 6, kcol = rem & 63;
                    ldsB[idx] = W_s[(size_t)(c0 + cl) * Kz + (ktp * 2 + t2) * 64 + kcol];
                }
                __syncthreads();
                #pragma unroll 4
                for (int ccx = 0; ccx < 64; ccx++) {
                    float4 av = *(const float4*)&ldsA[ccx * 64 + pq * 4];
                    float4 bv = *(const float4*)&ldsB[g * 4096 + ccx * 64 + kq * 4];
                    acc[0][0] = fmaf(av.x, bv.x, acc[0][0]);
                    acc[0][1] = fmaf(av.x, bv.y, acc[0][1]);
                    acc[0][2] = fmaf(av.x, bv.z, acc[0][2]);
                    acc[0][3] = fmaf(av.x, bv.w, acc[0][3]);
                    acc[1][0] = fmaf(av.y, bv.x, acc[1][0]);
                    acc[1][1] = fmaf(av.y, bv.y, acc[1][1]);
                    acc[1][2] = fmaf(av.y, bv.z, acc[1][2]);
                    acc[1][3] = fmaf(av.y, bv.w, acc[1][3]);
                    acc[2][0] = fmaf(av.z, bv.x, acc[2][0]);
                    acc[2][1] = fmaf(av.z, bv.y, acc[2][1]);
                    acc[2][2] = fmaf(av.z, bv.z, acc[2][2]);
                    acc[2][3] = fmaf(av.z, bv.w, acc[2][3]);
                    acc[3][0] = fmaf(av.w, bv.x, acc[3][0]);
                    acc[3][1] = fmaf(av.w, bv.y, acc[3][1]);
                    acc[3][2] = fmaf(av.w, bv.z, acc[3][2]);
                    acc[3][3] = fmaf(av.w, bv.w, acc[3][3]);
                }
            }
            float* dst = spart + (size_t)((cs * 8 + b) * 64) * Kz
                       + (ktp * 2 + g) * 64 + kq * 4;
            #pragma unroll
            for (int r = 0; r < 4; r++) {
                float4 w = make_float4(acc[r][0], acc[r][1], acc[r][2], acc[r][3]);
                *(float4*)(dst + (size_t)(pq * 4 + r) * Kz) = w;
            }
        }
        gbar(cnt, phase);

        // ---------- stage 4: spatial scores + softmax → alpha | xcat emb/h fill ----------
        {
            if (blk < 64) {
                int p = blk;
                int b = wave;
                float acc = 0.0f;
                #pragma unroll
                for (int i = 0; i < 8; i++) {
                    int k = i * 64 + lane;
                    float s = qs[b * Kz + k];
                    #pragma unroll
                    for (int csx = 0; csx < 8; csx++)
                        s += spart[(size_t)((csx * 8 + b) * 64 + p) * Kz + k];
                    acc += tanhf(s) * W_i[k];
                }
                acc = waveReduce(acc);
                if (lane == 0) sred[b] = acc;
                __syncthreads();
                if (tid < 8) {
                    float m = -1e30f;
                    #pragma unroll
                    for (int j = 0; j < 8; j++) m = fmaxf(m, sred[j]);
                    float s = 0.0f;
                    #pragma unroll
                    for (int j = 0; j < 8; j++) s += expf(sred[j] - m);
                    alpha[tid * Pz + p] = expf(sred[tid] - m) / s;
                }
            } else if (blk < 80) {
                int idx = (blk - 64) * 512 + tid;     // 0..8191
                int b = idx >> 10, r = idx & 1023;
                if (r < Ez) xcat[b * 3072 + r] = emb[(size_t)caps[b * T1z + t] * Ez + r];
                else        xcat[b * 3072 + 2560 + (r - Ez)] = h[b * Dz + (r - Ez)];
            }
        }
        gbar(cnt, phase);

        // ---------- stage 5: awe → xcat[b][512+c] ----------
        {
            int b = gw >> 8;
            int cg = gw & 255;
            float al = alpha[b * Pz + lane];
            #pragma unroll
            for (int r = 0; r < 8; r++) {
                int cc = cg * 8 + r;
                float vv = enc[(size_t)(b * Cz + cc) * 64 + lane] * al;
                vv = waveReduce(vv);
                if (lane == 0)
                    xcat[b * 3072 + Ez + cc] = beta[b * Cz + cc] * vv * (1.0f / 64.0f);
            }
        }
        gbar(cnt, phase);

        // ---------- stage 6: gates + cell ----------
        {
            int d0 = blk * 2;
            int g = wave >> 1, i2 = wave & 1;
            int j = g * 512 + d0 + i2;
            int bb = lane >> 3, e8 = lane & 7;
            const float4* xv4 = (const float4*)(xcat + bb * 3072);
            const float4* wih4 = (const float4*)(W_ih + (size_t)j * 2560);
            const float4* whh4 = (const float4*)(W_hh + (size_t)j * Dz);
            float acc0 = 0.0f, acc1 = 0.0f;
            #pragma unroll 8
            for (int q = 0; q < 80; q += 2) {
                float4 w0 = wih4[q * 8 + e8];
                float4 x0 = xv4[q * 8 + e8];
                float4 w1 = wih4[(q + 1) * 8 + e8];
                float4 x1 = xv4[(q + 1) * 8 + e8];
                acc0 = fmaf(x0.x, w0.x, acc0); acc0 = fmaf(x0.y, w0.y, acc0);
                acc0 = fmaf(x0.z, w0.z, acc0); acc0 = fmaf(x0.w, w0.w, acc0);
                acc1 = fmaf(x1.x, w1.x, acc1); acc1 = fmaf(x1.y, w1.y, acc1);
                acc1 = fmaf(x1.z, w1.z, acc1); acc1 = fmaf(x1.w, w1.w, acc1);
            }
            #pragma unroll
            for (int q = 80; q < 96; q += 2) {
                float4 w0 = whh4[(q - 80) * 8 + e8];
                float4 x0 = xv4[q * 8 + e8];
                float4 w1 = whh4[(q - 79) * 8 + e8];
                float4 x1 = xv4[(q + 1) * 8 + e8];
                acc0 = fmaf(x0.x, w0.x, acc0); acc0 = fmaf(x0.y, w0.y, acc0);
                acc0 = fmaf(x0.z, w0.z, acc0); acc0 = fmaf(x0.w, w0.w, acc0);
                acc1 = fmaf(x1.x, w1.x, acc1); acc1 = fmaf(x1.y, w1.y, acc1);
                acc1 = fmaf(x1.z, w1.z, acc1); acc1 = fmaf(x1.w, w1.w, acc1);
            }
            float acc = acc0 + acc1;
            acc += __shfl_xor(acc, 1);
            acc += __shfl_xor(acc, 2);
            acc += __shfl_xor(acc, 4);
            if (e8 == 0) sred[wave * 8 + bb] = acc;
            __syncthreads();
            if (tid < 16) {
                int bb2 = tid & 7, ii = (tid >> 3) & 1;
                int d = d0 + ii;
                float gI = sred[(0 + ii) * 8 + bb2] + b_ih[d]        + b_hh[d];
                float gF = sred[(2 + ii) * 8 + bb2] + b_ih[512 + d]  + b_hh[512 + d];
                float gG = sred[(4 + ii) * 8 + bb2] + b_ih[1024 + d] + b_hh[1024 + d];
                float gO = sred[(6 + ii) * 8 + bb2] + b_ih[1536 + d] + b_hh[1536 + d];
                float ig = sigf(gI), fg = sigf(gF), gt = tanhf(gG), og = sigf(gO);
                int idx = bb2 * Dz + d;
                float cn = fg * c[idx] + ig * gt;
                c[idx] = cn;
                h[idx] = og * tanhf(cn);
            }
        }
        gbar(cnt, phase);
    }

    // ---------------- final: preds(t=11) on all blocks ----------------
    predsWave(h, W_fc, b_fc, out, Tz - 1, gw * 10, 10, lane);
}

extern "C" void kernel_launch(void* const* d_in, const int* in_sizes, int n_in,
                              void* d_out, int out_size, void* d_ws, size_t ws_size,
                              hipStream_t stream) {
    const float* enc      = (const float*)d_in[0];
    const int*   caps     = (const int*)d_in[1];
    const int*   caplen   = (const int*)d_in[2];
    const float* W_c      = (const float*)d_in[3];
    const float* W_hc     = (const float*)d_in[4];
    const float* W_i_hat  = (const float*)d_in[5];
    const float* b_c      = (const float*)d_in[6];
    const float* W_s      = (const float*)d_in[8];
    const float* W_hs     = (const float*)d_in[9];
    const float* W_i      = (const float*)d_in[10];
    const float* b_s      = (const float*)d_in[11];
    const float* emb      = (const float*)d_in[13];
    const float* W_ih     = (const float*)d_in[14];
    const float* W_hh     = (const float*)d_in[15];
    const float* b_ih     = (const float*)d_in[16];
    const float* b_hh     = (const float*)d_in[17];
    const float* W_init_h = (const float*)d_in[18];
    const float* b_init_h = (const float*)d_in[19];
    const float* W_init_c = (const float*)d_in[20];
    const float* b_init_c = (const float*)d_in[21];
    const float* W_fc     = (const float*)d_in[22];
    const float* b_fc     = (const float*)d_in[23];
    float* out = (float*)d_out;
    float* ws  = (float*)d_ws;
    unsigned* cnt = (unsigned*)(ws + 74240 + 2097152);

    k_zero<<<1, 64, 0, stream>>>(cnt);
    k_main<<<NB, NT, 0, stream>>>(enc, caps, caplen, W_c, W_hc, W_i_hat, b_c,
                                  W_s, W_hs, W_i, b_s, emb, W_ih, W_hh, b_ih, b_hh,
                                  W_init_h, b_init_h, W_init_c, b_init_c, W_fc, b_fc,
                                  out, ws, cnt);
}

// Round 4
// 3229.511 us; speedup vs baseline: 1.1420x; 1.1420x over previous
//
#include <hip/hip_runtime.h>

#define NB 256
#define NT 512
#define Bz 8
#define T1z 13
#define Tz 12
#define Vz 20000
#define Ez 512
#define Dz 512
#define Kz 512
#define Cz 2048
#define Pz 64

__device__ __forceinline__ float cload(const float* p) {
    return __hip_atomic_load((float*)p, __ATOMIC_RELAXED, __HIP_MEMORY_SCOPE_AGENT);
}
__device__ __forceinline__ void cstore(float* p, float v) {
    __hip_atomic_store(p, v, __ATOMIC_RELAXED, __HIP_MEMORY_SCOPE_AGENT);
}
__device__ __forceinline__ void cadd(float* p, float v) {
    __hip_atomic_fetch_add(p, v, __ATOMIC_RELAXED, __HIP_MEMORY_SCOPE_AGENT);
}

__device__ __forceinline__ float waveReduce(float v) {
    #pragma unroll
    for (int off = 32; off > 0; off >>= 1) v += __shfl_xor(v, off);
    return v;
}

__device__ __forceinline__ float sigf(float x) {
    return 1.0f / (1.0f + expf(-x));
}

// grid barrier: __syncthreads drains each wave's vmem (compiler emits
// s_waitcnt vmcnt(0) before s_barrier), counter is a relaxed agent atomic
// (coherent at LLC) -> NO cache-maintenance instructions, weights stay cached.
__device__ __forceinline__ void gbar(unsigned* cnt, unsigned& phase) {
    __syncthreads();
    phase += NB;
    if (threadIdx.x == 0) {
        __hip_atomic_fetch_add(cnt, 1u, __ATOMIC_RELAXED, __HIP_MEMORY_SCOPE_AGENT);
        while (__hip_atomic_load(cnt, __ATOMIC_RELAXED, __HIP_MEMORY_SCOPE_AGENT) < phase)
            __builtin_amdgcn_s_sleep(2);
    }
    __syncthreads();
}

// wave computes nv preds rows starting at v0; h staged in LDS (hls4)
__device__ __forceinline__ void predsWave(const float4* hls4,
                                          const float* __restrict__ W_fc,
                                          const float* __restrict__ b_fc,
                                          float* __restrict__ out,
                                          int tt, int v0, int nv, int lane) {
    int bb = lane >> 3, d8 = lane & 7;
    float4 hreg[16];
    #pragma unroll
    for (int i = 0; i < 16; i++) hreg[i] = hls4[bb * 128 + i * 8 + d8];
    for (int j = 0; j < nv; j++) {
        int v = v0 + j;
        if (v < Vz) {
            const float4* Wv = (const float4*)(W_fc + (size_t)v * Dz);
            float acc = 0.0f;
            #pragma unroll
            for (int i = 0; i < 16; i++) {
                float4 w = Wv[i * 8 + d8];
                acc = fmaf(hreg[i].x, w.x, acc);
                acc = fmaf(hreg[i].y, w.y, acc);
                acc = fmaf(hreg[i].z, w.z, acc);
                acc = fmaf(hreg[i].w, w.w, acc);
            }
            acc += __shfl_xor(acc, 1);
            acc += __shfl_xor(acc, 2);
            acc += __shfl_xor(acc, 4);
            if (d8 == 0) out[((size_t)bb * Tz + tt) * Vz + v] = acc + b_fc[v];
        }
    }
}

__global__ void k_zero(unsigned* cnt) { if (threadIdx.x == 0) *cnt = 0u; }

__global__ __launch_bounds__(NT, 2) void k_main(
    const float* __restrict__ enc, const int* __restrict__ caps,
    const int* __restrict__ caplen,
    const float* __restrict__ W_c, const float* __restrict__ W_hc,
    const float* __restrict__ W_i_hat, const float* __restrict__ b_c,
    const float* __restrict__ W_s, const float* __restrict__ W_hs,
    const float* __restrict__ W_i, const float* __restrict__ b_s,
    const float* __restrict__ emb, const float* __restrict__ W_ih,
    const float* __restrict__ W_hh, const float* __restrict__ b_ih,
    const float* __restrict__ b_hh, const float* __restrict__ W_init_h,
    const float* __restrict__ b_init_h, const float* __restrict__ W_init_c,
    const float* __restrict__ b_init_c, const float* __restrict__ W_fc,
    const float* __restrict__ b_fc,
    float* __restrict__ out, float* __restrict__ ws, unsigned* cnt)
{
    const int blk = blockIdx.x, tid = threadIdx.x;
    const int wave = tid >> 6, lane = tid & 63;
    const int gw = blk * 8 + wave;            // 0..2047
    unsigned phase = 0;

    float* vmean = ws;                        // 16384
    float* h     = ws + 16384;                // 4096
    float* c     = ws + 20480;                // 4096
    float* qc0   = ws + 24576;                // 4096
    float* qs0   = ws + 28672;                // 4096
    float* qc1   = ws + 32768;                // 4096
    float* qs1   = ws + 36864;                // 4096
    float* beta  = ws + 40960;                // 16384
    float* alpha = ws + 57344;                // 512
    float* xcat  = ws + 57856;                // 24576
    float* spart = ws + 82432;                // 2097152

    __shared__ __align__(16) float smem[12288];   // 48 KB, stage-aliased
    __shared__ float sred[128];

    // ---------------- stage 0a: vmean + tail + qbuf0 init ----------------
    #pragma unroll
    for (int r = 0; r < 8; r++) {
        int row = gw * 8 + r;                 // (b*C + c)
        float v = enc[(size_t)row * 64 + lane];
        v = waveReduce(v);
        if (lane == 0) cstore(&vmean[row], v * (1.0f / 64.0f));
    }
    if (blk == 0) {
        const int base = Bz * Tz * Vz;
        const int nCap = Bz * T1z, nLen = Bz, nAlp = Bz * Tz * Pz;
        for (int idx = tid; idx < nCap + nLen + nAlp + Bz; idx += NT) {
            float val;
            if (idx < nCap) val = (float)caps[idx];
            else if (idx < nCap + nLen) val = (float)(caplen[idx - nCap] - 1);
            else if (idx < nCap + nLen + nAlp) val = 0.0f;
            else val = (float)(idx - (nCap + nLen + nAlp));
            out[base + idx] = val;
        }
    } else if (blk == 1) {
        for (int idx = tid; idx < Bz * Kz; idx += NT)
            cstore(&qc0[idx], b_c[idx & 511]);
    } else if (blk == 2) {
        for (int idx = tid; idx < Bz * Kz; idx += NT)
            cstore(&qs0[idx], b_s[idx & 511]);
    }
    gbar(cnt, phase);

    // ---------------- stage 0b: h0, c0 (one (which,b) per block) ----------------
    {
        int which = blk >> 7;                 // 0: h, 1: c
        int b = (blk >> 4) & 7;
        const float* W = which ? W_init_c : W_init_h;
        #pragma unroll
        for (int i = 0; i < 4; i++)
            smem[i * 512 + tid] = cload(&vmean[b * Cz + i * 512 + tid]);
        __syncthreads();
        const float4* vls4 = (const float4*)smem;
        #pragma unroll
        for (int r = 0; r < 4; r++) {
            int d = (blk & 15) * 32 + wave * 4 + r;
            const float4* W4 = (const float4*)(W + (size_t)d * Cz);
            float acc = 0.0f;
            #pragma unroll
            for (int i = 0; i < 8; i++) {
                float4 wv = W4[i * 64 + lane];
                float4 xv = vls4[i * 64 + lane];
                acc = fmaf(wv.x, xv.x, acc); acc = fmaf(wv.y, xv.y, acc);
                acc = fmaf(wv.z, xv.z, acc); acc = fmaf(wv.w, xv.w, acc);
            }
            acc = waveReduce(acc);
            if (lane == 0) {
                if (which) cstore(&c[b * Dz + d], acc + b_init_c[d]);
                else       cstore(&h[b * Dz + d], acc + b_init_h[d]);
            }
        }
    }
    gbar(cnt, phase);

    for (int t = 0; t < Tz; t++) {
        float* qc_cur = (t & 1) ? qc1 : qc0;
        float* qs_cur = (t & 1) ? qs1 : qs0;
        float* qc_nxt = (t & 1) ? qc0 : qc1;
        float* qs_nxt = (t & 1) ? qs0 : qs1;

        // ---------- stage 1: qc/qs partial GEMV (64 blk) | preds(t-1) (192 blk) ----------
        if (blk < 64) {
            int b = blk & 7, which = (blk >> 3) & 1, dch = blk >> 4;
            int d0 = dch * 128;
            const float* W = which ? W_hs : W_hc;
            if (tid < 128) smem[tid] = cload(&h[b * Dz + d0 + tid]);
            __syncthreads();
            int k = tid;
            float a0 = 0.f, a1 = 0.f, a2 = 0.f, a3 = 0.f;
            #pragma unroll 4
            for (int dd = 0; dd < 128; dd += 4) {
                a0 = fmaf(smem[dd],     W[(size_t)(d0 + dd)     * Kz + k], a0);
                a1 = fmaf(smem[dd + 1], W[(size_t)(d0 + dd + 1) * Kz + k], a1);
                a2 = fmaf(smem[dd + 2], W[(size_t)(d0 + dd + 2) * Kz + k], a2);
                a3 = fmaf(smem[dd + 3], W[(size_t)(d0 + dd + 3) * Kz + k], a3);
            }
            cadd(&(which ? qs_cur : qc_cur)[b * Kz + k], (a0 + a1) + (a2 + a3));
        } else if (t > 0) {
            #pragma unroll
            for (int i = 0; i < 8; i++)
                smem[i * 512 + tid] = cload(&h[i * 512 + tid]);
            __syncthreads();
            int gw2 = (blk - 64) * 8 + wave;  // 0..1535
            predsWave((const float4*)smem, W_fc, b_fc, out, t - 1, gw2 * 14, 14, lane);
        }
        gbar(cnt, phase);

        // ---------- stage 2: channel attention + batch softmax → beta ----------
        {
            int cg = blk;                     // 8 channels per block
            int b = wave;
            float* qslot = smem + wave * 512;
            #pragma unroll
            for (int q = 0; q < 8; q++)
                qslot[q * 64 + lane] = cload(&qc_cur[b * Kz + q * 64 + lane]);
            int c8 = lane >> 3, k8 = lane & 7;
            int cc = cg * 8 + c8;
            float v = cload(&vmean[b * Cz + cc]);
            float acc = 0.0f;
            #pragma unroll 8
            for (int i = 0; i < 64; i++) {
                int k = i * 8 + k8;
                acc += tanhf(fmaf(v, W_c[k], qslot[k])) * W_i_hat[k];
            }
            acc += __shfl_xor(acc, 1);
            acc += __shfl_xor(acc, 2);
            acc += __shfl_xor(acc, 4);
            if (k8 == 0) sred[c8 * 8 + b] = acc;
            __syncthreads();
            if (tid < 64) {
                int c8_ = tid >> 3, b_ = tid & 7;
                float m = -1e30f;
                #pragma unroll
                for (int j = 0; j < 8; j++) m = fmaxf(m, sred[c8_ * 8 + j]);
                float s = 0.0f;
                #pragma unroll
                for (int j = 0; j < 8; j++) s += expf(sred[c8_ * 8 + j] - m);
                cstore(&beta[b_ * Cz + cg * 8 + c8_], expf(sred[c8_ * 8 + b_] - m) / s);
            }
        }
        gbar(cnt, phase);

        // ---------- stage 3: einsum partials spart[cs][b][p][k] ----------
        {
            float* ldsA = smem;               // 4096
            float* ldsB = smem + 4096;        // 8192
            int cs = blk >> 5;                // 0..7
            int ktp = (blk >> 3) & 3;         // 0..3
            int b = blk & 7;
            int g = tid >> 8;
            int tl = tid & 255;
            int kq = tl & 15, pq = tl >> 4;
            float acc[4][4] = {};
            for (int chunk = 0; chunk < 4; chunk++) {
                int c0 = cs * 256 + chunk * 64;
                __syncthreads();
                #pragma unroll
                for (int i = 0; i < 8; i++) {
                    int idx = tid + i * 512;
                    int cl = idx >> 6, p = idx & 63;
                    ldsA[idx] = enc[(size_t)(b * Cz + c0 + cl) * 64 + p]
                              * cload(&beta[b * Cz + c0 + cl]);
                }
                #pragma unroll
                for (int i = 0; i < 16; i++) {
                    int idx = tid + i * 512;
                    int t2 = idx >> 12, rem = idx & 4095;
                    int cl = rem >> 6, kcol = rem & 63;
                    ldsB[idx] = W_s[(size_t)(c0 + cl) * Kz + (ktp * 2 + t2) * 64 + kcol];
                }
                __syncthreads();
                #pragma unroll 4
                for (int ccx = 0; ccx < 64; ccx++) {
                    float4 av = *(const float4*)&ldsA[ccx * 64 + pq * 4];
                    float4 bv = *(const float4*)&ldsB[g * 4096 + ccx * 64 + kq * 4];
                    acc[0][0] = fmaf(av.x, bv.x, acc[0][0]);
                    acc[0][1] = fmaf(av.x, bv.y, acc[0][1]);
                    acc[0][2] = fmaf(av.x, bv.z, acc[0][2]);
                    acc[0][3] = fmaf(av.x, bv.w, acc[0][3]);
                    acc[1][0] = fmaf(av.y, bv.x, acc[1][0]);
                    acc[1][1] = fmaf(av.y, bv.y, acc[1][1]);
                    acc[1][2] = fmaf(av.y, bv.z, acc[1][2]);
                    acc[1][3] = fmaf(av.y, bv.w, acc[1][3]);
                    acc[2][0] = fmaf(av.z, bv.x, acc[2][0]);
                    acc[2][1] = fmaf(av.z, bv.y, acc[2][1]);
                    acc[2][2] = fmaf(av.z, bv.z, acc[2][2]);
                    acc[2][3] = fmaf(av.z, bv.w, acc[2][3]);
                    acc[3][0] = fmaf(av.w, bv.x, acc[3][0]);
                    acc[3][1] = fmaf(av.w, bv.y, acc[3][1]);
                    acc[3][2] = fmaf(av.w, bv.z, acc[3][2]);
                    acc[3][3] = fmaf(av.w, bv.w, acc[3][3]);
                }
            }
            float* dst = spart + (size_t)((cs * 8 + b) * 64) * Kz
                       + (ktp * 2 + g) * 64 + kq * 4;
            #pragma unroll
            for (int r = 0; r < 4; r++) {
                float* dp = dst + (size_t)(pq * 4 + r) * Kz;
                cstore(dp + 0, acc[r][0]); cstore(dp + 1, acc[r][1]);
                cstore(dp + 2, acc[r][2]); cstore(dp + 3, acc[r][3]);
            }
        }
        gbar(cnt, phase);

        // ---------- stage 4: scores+softmax→alpha | xcat emb/h | qbuf-next init ----------
        {
            if (blk < 64) {
                int p = blk;
                int b = wave;
                float acc = 0.0f;
                #pragma unroll
                for (int i = 0; i < 8; i++) {
                    int k = i * 64 + lane;
                    float s = cload(&qs_cur[b * Kz + k]);
                    #pragma unroll
                    for (int csx = 0; csx < 8; csx++)
                        s += cload(&spart[(size_t)((csx * 8 + b) * 64 + p) * Kz + k]);
                    acc += tanhf(s) * W_i[k];
                }
                acc = waveReduce(acc);
                if (lane == 0) sred[b] = acc;
                __syncthreads();
                if (tid < 8) {
                    float m = -1e30f;
                    #pragma unroll
                    for (int j = 0; j < 8; j++) m = fmaxf(m, sred[j]);
                    float s = 0.0f;
                    #pragma unroll
                    for (int j = 0; j < 8; j++) s += expf(sred[j] - m);
                    cstore(&alpha[tid * Pz + p], expf(sred[tid] - m) / s);
                }
            } else if (blk < 80) {
                int idx = (blk - 64) * 512 + tid;     // 0..8191
                int b = idx >> 10, r = idx & 1023;
                if (r < Ez) cstore(&xcat[b * 3072 + r],
                                   emb[(size_t)caps[b * T1z + t] * Ez + r]);
                else        cstore(&xcat[b * 3072 + 2560 + (r - Ez)],
                                   cload(&h[b * Dz + (r - Ez)]));
            } else if (blk < 96) {
                int idx = (blk - 80) * 512 + tid;     // 0..8191
                if (idx < 4096) cstore(&qc_nxt[idx], b_c[idx & 511]);
                else            cstore(&qs_nxt[idx - 4096], b_s[idx & 511]);
            }
        }
        gbar(cnt, phase);

        // ---------- stage 5: awe → xcat[b][512+c] ----------
        {
            int b = gw >> 8;
            int cg = gw & 255;
            float al = cload(&alpha[b * Pz + lane]);
            #pragma unroll
            for (int r = 0; r < 8; r++) {
                int cc = cg * 8 + r;
                float vv = enc[(size_t)(b * Cz + cc) * 64 + lane] * al;
                vv = waveReduce(vv);
                if (lane == 0)
                    cstore(&xcat[b * 3072 + Ez + cc],
                           cload(&beta[b * Cz + cc]) * vv * (1.0f / 64.0f));
            }
        }
        gbar(cnt, phase);

        // ---------- stage 6: gates + cell (wave = b, lanes = (j8, e8)) ----------
        {
            int d0 = blk * 2;
            int w = wave;                     // batch index
            int jj = lane >> 3, e8 = lane & 7;
            int j = (jj >> 1) * 512 + d0 + (jj & 1);
            float* xslot = smem + wave * 1024;
            const float4* xslot4 = (const float4*)xslot;
            float acc = 0.0f;
            for (int seg = 0; seg < 3; seg++) {
                #pragma unroll
                for (int q = 0; q < 16; q++)
                    xslot[q * 64 + lane] = cload(&xcat[w * 3072 + seg * 1024 + q * 64 + lane]);
                #pragma unroll 8
                for (int q2 = 0; q2 < 32; q2++) {
                    float4 xv = xslot4[q2 * 8 + e8];
                    int ge = seg * 1024 + q2 * 32 + e8 * 4;
                    const float* wp = (ge < 2560)
                        ? (W_ih + (size_t)j * 2560 + ge)
                        : (W_hh + (size_t)j * Dz + (ge - 2560));
                    float4 wv = *(const float4*)wp;
                    acc = fmaf(xv.x, wv.x, acc); acc = fmaf(xv.y, wv.y, acc);
                    acc = fmaf(xv.z, wv.z, acc); acc = fmaf(xv.w, wv.w, acc);
                }
            }
            acc += __shfl_xor(acc, 1);
            acc += __shfl_xor(acc, 2);
            acc += __shfl_xor(acc, 4);
            if (e8 == 0) sred[jj * 8 + w] = acc;
            __syncthreads();
            if (tid < 16) {
                int bb2 = tid & 7, ii = (tid >> 3) & 1;
                int d = d0 + ii;
                float gI = sred[(0 + ii) * 8 + bb2] + b_ih[d]        + b_hh[d];
                float gF = sred[(2 + ii) * 8 + bb2] + b_ih[512 + d]  + b_hh[512 + d];
                float gG = sred[(4 + ii) * 8 + bb2] + b_ih[1024 + d] + b_hh[1024 + d];
                float gO = sred[(6 + ii) * 8 + bb2] + b_ih[1536 + d] + b_hh[1536 + d];
                float ig = sigf(gI), fg = sigf(gF), gt = tanhf(gG), og = sigf(gO);
                int idx = bb2 * Dz + d;
                float cn = fg * cload(&c[idx]) + ig * gt;
                cstore(&c[idx], cn);
                cstore(&h[idx], og * tanhf(cn));
            }
        }
        gbar(cnt, phase);
    }

    // ---------------- final: preds(t=11) on all blocks ----------------
    #pragma unroll
    for (int i = 0; i < 8; i++)
        smem[i * 512 + tid] = cload(&h[i * 512 + tid]);
    __syncthreads();
    predsWave((const float4*)smem, W_fc, b_fc, out, Tz - 1, gw * 10, 10, lane);
}

extern "C" void kernel_launch(void* const* d_in, const int* in_sizes, int n_in,
                              void* d_out, int out_size, void* d_ws, size_t ws_size,
                              hipStream_t stream) {
    const float* enc      = (const float*)d_in[0];
    const int*   caps     = (const int*)d_in[1];
    const int*   caplen   = (const int*)d_in[2];
    const float* W_c      = (const float*)d_in[3];
    const float* W_hc     = (const float*)d_in[4];
    const float* W_i_hat  = (const float*)d_in[5];
    const float* b_c      = (const float*)d_in[6];
    const float* W_s      = (const float*)d_in[8];
    const float* W_hs     = (const float*)d_in[9];
    const float* W_i      = (const float*)d_in[10];
    const float* b_s      = (const float*)d_in[11];
    const float* emb      = (const float*)d_in[13];
    const float* W_ih     = (const float*)d_in[14];
    const float* W_hh     = (const float*)d_in[15];
    const float* b_ih     = (const float*)d_in[16];
    const float* b_hh     = (const float*)d_in[17];
    const float* W_init_h = (const float*)d_in[18];
    const float* b_init_h = (const float*)d_in[19];
    const float* W_init_c = (const float*)d_in[20];
    const float* b_init_c = (const float*)d_in[21];
    const float* W_fc     = (const float*)d_in[22];
    const float* b_fc     = (const float*)d_in[23];
    float* out = (float*)d_out;
    float* ws  = (float*)d_ws;
    unsigned* cnt = (unsigned*)(ws + 82432 + 2097152);

    k_zero<<<1, 64, 0, stream>>>(cnt);
    k_main<<<NB, NT, 0, stream>>>(enc, caps, caplen, W_c, W_hc, W_i_hat, b_c,
                                  W_s, W_hs, W_i, b_s, emb, W_ih, W_hh, b_ih, b_hh,
                                  W_init_h, b_init_h, W_init_c, b_init_c, W_fc, b_fc,
                                  out, ws, cnt);
}

// Round 5
// 1499.126 us; speedup vs baseline: 2.4602x; 2.1543x over previous
//
#include <hip/hip_runtime.h>

#define Bz 8
#define T1z 13
#define Tz 12
#define Vz 20000
#define Ez 512
#define Dz 512
#define Kz 512
#define Cz 2048
#define Pz 64

// bf16 element counts / offsets in the converted-weight pool
#define N_WFC  10240000
#define N_WIH  5242880
#define N_WHH  1048576
#define N_WS   1048576
#define N_WHC  262144
#define N_WHS  262144
#define NB16   18104320   // total bf16 elems
#define O_WIH  10240000
#define O_WHH  15482880
#define O_WS   16531456
#define O_WHC  17580032
#define O_WHS  17842176

__device__ __forceinline__ unsigned short f2b(float x) {
    unsigned u = __float_as_uint(x);
    return (unsigned short)((u + 0x7fffu + ((u >> 16) & 1u)) >> 16);
}
__device__ __forceinline__ float bLO(unsigned u) { return __uint_as_float(u << 16); }
__device__ __forceinline__ float bHI(unsigned u) { return __uint_as_float(u & 0xffff0000u); }

__device__ __forceinline__ float waveReduce(float v) {
    #pragma unroll
    for (int off = 32; off > 0; off >>= 1) v += __shfl_xor(v, off);
    return v;
}
__device__ __forceinline__ float sigf(float x) { return 1.0f / (1.0f + expf(-x)); }

// one wave computes 4 consecutive preds rows starting at v0 (bf16 W_fc)
__device__ __forceinline__ void predsWave(const float* __restrict__ h,
                                          const unsigned short* __restrict__ Wfc,
                                          const float* __restrict__ b_fc,
                                          float* __restrict__ out,
                                          int tt, int v0, int lane) {
    int bb = lane >> 3, d8 = lane & 7;
    const float4* h4 = (const float4*)(h + bb * Dz);
    float4 hreg[16];
    #pragma unroll
    for (int i = 0; i < 8; i++) {
        hreg[2 * i]     = h4[i * 16 + d8 * 2];
        hreg[2 * i + 1] = h4[i * 16 + d8 * 2 + 1];
    }
    #pragma unroll
    for (int j = 0; j < 4; j++) {
        int v = v0 + j;
        if (v < Vz) {
            const uint4* W4 = (const uint4*)(Wfc + (size_t)v * Dz);
            float acc = 0.0f;
            #pragma unroll
            for (int i = 0; i < 8; i++) {
                uint4 w = W4[i * 8 + d8];
                float4 ha = hreg[2 * i], hb = hreg[2 * i + 1];
                acc = fmaf(ha.x, bLO(w.x), acc); acc = fmaf(ha.y, bHI(w.x), acc);
                acc = fmaf(ha.z, bLO(w.y), acc); acc = fmaf(ha.w, bHI(w.y), acc);
                acc = fmaf(hb.x, bLO(w.z), acc); acc = fmaf(hb.y, bHI(w.z), acc);
                acc = fmaf(hb.z, bLO(w.w), acc); acc = fmaf(hb.w, bHI(w.w), acc);
            }
            acc += __shfl_xor(acc, 1);
            acc += __shfl_xor(acc, 2);
            acc += __shfl_xor(acc, 4);
            if (d8 == 0) out[((size_t)bb * Tz + tt) * Vz + v] = acc + b_fc[v];
        }
    }
}

// ---- prep: convert 6 weight matrices to bf16 + vmean + tail outputs ----
__global__ __launch_bounds__(256) void k_prep(
    const float* __restrict__ W_fc, const float* __restrict__ W_ih,
    const float* __restrict__ W_hh, const float* __restrict__ W_s,
    const float* __restrict__ W_hc, const float* __restrict__ W_hs,
    const float* __restrict__ enc, const int* __restrict__ caps,
    const int* __restrict__ caplen,
    unsigned short* __restrict__ wb, float* __restrict__ vmean,
    float* __restrict__ out) {
    int blk = blockIdx.x, tid = threadIdx.x;
    if (blk < 4096) {
        int gid = blk * 256 + tid;
        #pragma unroll
        for (int it = 0; it < 5; it++) {
            int idx4 = gid + it * 1048576;
            if (idx4 < NB16 / 4) {
                int e = idx4 * 4;
                const float* src; int off;
                if (e < O_WIH)      { src = W_fc; off = e; }
                else if (e < O_WHH) { src = W_ih; off = e - O_WIH; }
                else if (e < O_WS)  { src = W_hh; off = e - O_WHH; }
                else if (e < O_WHC) { src = W_s;  off = e - O_WS; }
                else if (e < O_WHS) { src = W_hc; off = e - O_WHC; }
                else                { src = W_hs; off = e - O_WHS; }
                float4 f = *(const float4*)(src + off);
                ushort4 o = { f2b(f.x), f2b(f.y), f2b(f.z), f2b(f.w) };
                *(ushort4*)(wb + e) = o;
            }
        }
    } else if (blk < 4352) {
        int wave = tid >> 6, lane = tid & 63;
        int base = (blk - 4096) * 64 + wave * 16;
        #pragma unroll
        for (int r = 0; r < 16; r++) {
            int row = base + r;
            float v = enc[(size_t)row * 64 + lane];
            v = waveReduce(v);
            if (lane == 0) vmean[row] = v * (1.0f / 64.0f);
        }
    } else {
        const int base = Bz * Tz * Vz;
        const int nCap = Bz * T1z, nLen = Bz, nAlp = Bz * Tz * Pz;
        for (int idx = tid; idx < nCap + nLen + nAlp + Bz; idx += 256) {
            float val;
            if (idx < nCap) val = (float)caps[idx];
            else if (idx < nCap + nLen) val = (float)(caplen[idx - nCap] - 1);
            else if (idx < nCap + nLen + nAlp) val = 0.0f;
            else val = (float)(idx - (nCap + nLen + nAlp));
            out[base + idx] = val;
        }
    }
}

// ---- h0, c0 ----
__global__ __launch_bounds__(256) void k_init(
    const float* __restrict__ vmean,
    const float* __restrict__ Wh, const float* __restrict__ bh,
    const float* __restrict__ Wc, const float* __restrict__ bc,
    float* __restrict__ h, float* __restrict__ c) {
    __shared__ float sm[2048];
    int blk = blockIdx.x, tid = threadIdx.x;
    int wave = tid >> 6, lane = tid & 63;
    int which = blk >> 7, b = (blk >> 4) & 7, d0 = (blk & 15) * 32;
    #pragma unroll
    for (int i = 0; i < 8; i++) sm[tid + i * 256] = vmean[b * Cz + tid + i * 256];
    __syncthreads();
    const float* W = which ? Wc : Wh;
    const float4* vm4 = (const float4*)sm;
    #pragma unroll
    for (int r = 0; r < 8; r++) {
        int d = d0 + wave * 8 + r;
        const float4* W4 = (const float4*)(W + (size_t)d * Cz);
        float acc = 0.0f;
        #pragma unroll
        for (int i = 0; i < 8; i++) {
            float4 wv = W4[i * 64 + lane];
            float4 xv = vm4[i * 64 + lane];
            acc = fmaf(wv.x, xv.x, acc); acc = fmaf(wv.y, xv.y, acc);
            acc = fmaf(wv.z, xv.z, acc); acc = fmaf(wv.w, xv.w, acc);
        }
        acc = waveReduce(acc);
        if (lane == 0) {
            if (which) c[b * Dz + d] = acc + bc[d];
            else       h[b * Dz + d] = acc + bh[d];
        }
    }
}

// ---- k1: qcqs (16 blocks, all-b shared weights) | preds(t-1) v[0,4800) ----
__global__ __launch_bounds__(256) void k1(
    const float* __restrict__ h, const unsigned short* __restrict__ wb,
    const float* __restrict__ b_c, const float* __restrict__ b_s,
    const float* __restrict__ b_fc,
    float* __restrict__ qc, float* __restrict__ qs,
    float* __restrict__ out, int t) {
    __shared__ float hL[512];
    int blk = blockIdx.x, tid = threadIdx.x;
    int wave = tid >> 6, lane = tid & 63;
    if (blk < 16) {
        int which = blk >> 3, d0 = (blk & 7) * 64;
        #pragma unroll
        for (int i = 0; i < 2; i++) {
            int idx = tid + i * 256;
            hL[idx] = h[(idx >> 6) * Dz + d0 + (idx & 63)];
        }
        __syncthreads();
        const unsigned short* W = wb + (which ? O_WHS : O_WHC);
        int k0 = tid * 2;
        float a[16] = {};
        for (int dd = 0; dd < 64; dd++) {
            unsigned u = *(const unsigned*)(W + (size_t)(d0 + dd) * Kz + k0);
            float f0 = bLO(u), f1 = bHI(u);
            #pragma unroll
            for (int b = 0; b < 8; b++) {
                float hv = hL[b * 64 + dd];
                a[b * 2]     = fmaf(hv, f0, a[b * 2]);
                a[b * 2 + 1] = fmaf(hv, f1, a[b * 2 + 1]);
            }
        }
        float* q = which ? qs : qc;
        const float* bias = which ? b_s : b_c;
        #pragma unroll
        for (int b = 0; b < 8; b++) {
            atomicAdd(&q[b * Kz + k0],     a[b * 2]);
            atomicAdd(&q[b * Kz + k0 + 1], a[b * 2 + 1]);
        }
        (void)bias;
    } else if (t > 0) {
        int gw2 = (blk - 16) * 4 + wave;
        predsWave(h, wb, b_fc, out, t - 1, gw2 * 4, lane);
    }
}

// ---- k1b: re-init qc/qs with biases for NEXT use (runs before k1 via k6 fold) ---
// (bias init folded into k6/k_init instead — see k_binit)
__global__ __launch_bounds__(256) void k_binit(const float* __restrict__ b_c,
                                               const float* __restrict__ b_s,
                                               float* __restrict__ qc,
                                               float* __restrict__ qs) {
    int idx = blockIdx.x * 256 + threadIdx.x;   // [0, 8192)
    if (idx < 4096) qc[idx] = b_c[idx & 511];
    else            qs[idx - 4096] = b_s[idx & 511];
}

// ---- k2: channel attention + batch softmax -> beta, and abf = bf16(enc*beta) ----
__global__ __launch_bounds__(256) void k2(
    const float* __restrict__ vmean, const float* __restrict__ W_c,
    const float* __restrict__ qc, const float* __restrict__ W_i_hat,
    const float* __restrict__ enc,
    float* __restrict__ beta, unsigned short* __restrict__ abf) {
    __shared__ float qcL[4096];
    __shared__ float sL[64];
    __shared__ float bL[64];
    int blk = blockIdx.x, tid = threadIdx.x;
    #pragma unroll
    for (int i = 0; i < 16; i++) qcL[tid + i * 256] = qc[tid + i * 256];
    __syncthreads();
    int c8 = tid >> 5, lane32 = tid & 31;
    int c = blk * 8 + c8;
    #pragma unroll
    for (int b = 0; b < 8; b++) {
        float v = vmean[b * Cz + c];
        float acc = 0.0f;
        #pragma unroll 4
        for (int i = 0; i < 16; i++) {
            int k = i * 32 + lane32;
            acc += tanhf(fmaf(v, W_c[k], qcL[b * Kz + k])) * W_i_hat[k];
        }
        acc += __shfl_xor(acc, 16); acc += __shfl_xor(acc, 8);
        acc += __shfl_xor(acc, 4);  acc += __shfl_xor(acc, 2);
        acc += __shfl_xor(acc, 1);
        if (lane32 == 0) sL[c8 * 8 + b] = acc;
    }
    __syncthreads();
    if (tid < 64) {
        int c8_ = tid >> 3, b_ = tid & 7;
        float m = -1e30f;
        #pragma unroll
        for (int j = 0; j < 8; j++) m = fmaxf(m, sL[c8_ * 8 + j]);
        float s = 0.0f;
        #pragma unroll
        for (int j = 0; j < 8; j++) s += expf(sL[c8_ * 8 + j] - m);
        float bv = expf(sL[c8_ * 8 + b_] - m) / s;
        beta[b_ * Cz + blk * 8 + c8_] = bv;
        bL[c8_ * 8 + b_] = bv;
    }
    __syncthreads();
    {
        int r = tid >> 2, pq = (tid & 3) * 16;
        int b = r >> 3, c8_ = r & 7;
        int cc = blk * 8 + c8_;
        float bv = bL[c8_ * 8 + b];
        const float* ep = enc + (size_t)(b * Cz + cc) * 64 + pq;
        unsigned short* ap = abf + (size_t)(b * Cz + cc) * 64 + pq;
        #pragma unroll
        for (int q = 0; q < 4; q++) {
            float4 e = *(const float4*)(ep + q * 4);
            ushort4 st = { f2b(e.x * bv), f2b(e.y * bv), f2b(e.z * bv), f2b(e.w * bv) };
            *(ushort4*)(ap + q * 4) = st;
        }
    }
}

// ---- k3: einsum partials spart[cs4][b][p][k] (bf16 A from abf, bf16 W_s) | preds ----
__global__ __launch_bounds__(256) void k3(
    const unsigned short* __restrict__ abf, const unsigned short* __restrict__ wb,
    const float* __restrict__ h, const float* __restrict__ b_fc,
    float* __restrict__ spart, float* __restrict__ out, int t) {
    __shared__ __align__(16) float ldsA[4096];
    __shared__ __align__(16) float ldsB[4096];
    int blk = blockIdx.x, tid = threadIdx.x;
    int wave = tid >> 6, lane = tid & 63;
    if (blk < 256) {
        const unsigned short* Ws = wb + O_WS;
        int cs = blk & 3, kt = (blk >> 2) & 7, b = blk >> 5;
        int kq = tid & 15, pq = tid >> 4;
        float acc[4][4] = {};
        for (int chunk = 0; chunk < 8; chunk++) {
            int c0 = cs * 512 + chunk * 64;
            __syncthreads();
            #pragma unroll
            for (int i = 0; i < 2; i++) {
                int run = tid + i * 256;
                int idx = run * 8;
                int cl = idx >> 6, x0 = idx & 63;
                uint4 ua = *(const uint4*)(abf + (size_t)(b * Cz + c0 + cl) * 64 + x0);
                float* dA = ldsA + idx;
                dA[0] = bLO(ua.x); dA[1] = bHI(ua.x); dA[2] = bLO(ua.y); dA[3] = bHI(ua.y);
                dA[4] = bLO(ua.z); dA[5] = bHI(ua.z); dA[6] = bLO(ua.w); dA[7] = bHI(ua.w);
                uint4 ub = *(const uint4*)(Ws + (size_t)(c0 + cl) * Kz + kt * 64 + x0);
                float* dB = ldsB + idx;
                dB[0] = bLO(ub.x); dB[1] = bHI(ub.x); dB[2] = bLO(ub.y); dB[3] = bHI(ub.y);
                dB[4] = bLO(ub.z); dB[5] = bHI(ub.z); dB[6] = bLO(ub.w); dB[7] = bHI(ub.w);
            }
            __syncthreads();
            #pragma unroll 4
            for (int cc = 0; cc < 64; cc++) {
                float4 av = *(const float4*)&ldsA[cc * 64 + pq * 4];
                float4 bv = *(const float4*)&ldsB[cc * 64 + kq * 4];
                acc[0][0] = fmaf(av.x, bv.x, acc[0][0]);
                acc[0][1] = fmaf(av.x, bv.y, acc[0][1]);
                acc[0][2] = fmaf(av.x, bv.z, acc[0][2]);
                acc[0][3] = fmaf(av.x, bv.w, acc[0][3]);
                acc[1][0] = fmaf(av.y, bv.x, acc[1][0]);
                acc[1][1] = fmaf(av.y, bv.y, acc[1][1]);
                acc[1][2] = fmaf(av.y, bv.z, acc[1][2]);
                acc[1][3] = fmaf(av.y, bv.w, acc[1][3]);
                acc[2][0] = fmaf(av.z, bv.x, acc[2][0]);
                acc[2][1] = fmaf(av.z, bv.y, acc[2][1]);
                acc[2][2] = fmaf(av.z, bv.z, acc[2][2]);
                acc[2][3] = fmaf(av.z, bv.w, acc[2][3]);
                acc[3][0] = fmaf(av.w, bv.x, acc[3][0]);
                acc[3][1] = fmaf(av.w, bv.y, acc[3][1]);
                acc[3][2] = fmaf(av.w, bv.z, acc[3][2]);
                acc[3][3] = fmaf(av.w, bv.w, acc[3][3]);
            }
        }
        float* dst = spart + (size_t)((cs * Bz + b) * Pz) * Kz + kt * 64 + kq * 4;
        #pragma unroll
        for (int r = 0; r < 4; r++) {
            float4 w = make_float4(acc[r][0], acc[r][1], acc[r][2], acc[r][3]);
            *(float4*)(dst + (size_t)(pq * 4 + r) * Kz) = w;
        }
    } else if (t > 0) {
        int gw2 = (blk - 256) * 4 + wave;
        predsWave(h, wb, b_fc, out, t - 1, 4800 + gw2 * 4, lane);
    }
}

// ---- k4: spatial scores + batch softmax -> alpha | preds ----
__global__ __launch_bounds__(512) void k4(
    const float* __restrict__ spart, const float* __restrict__ qs,
    const float* __restrict__ W_i, const float* __restrict__ b_i,
    const float* __restrict__ h, const unsigned short* __restrict__ wb,
    const float* __restrict__ b_fc,
    float* __restrict__ alpha, float* __restrict__ out, int t) {
    __shared__ float sL[8];
    int blk = blockIdx.x, tid = threadIdx.x;
    int wave = tid >> 6, lane = tid & 63;
    if (blk < 64) {
        int p = blk, b = wave;
        int k0 = lane * 8;
        float4 q0 = *(const float4*)(qs + b * Kz + k0);
        float4 q1 = *(const float4*)(qs + b * Kz + k0 + 4);
        #pragma unroll
        for (int cs = 0; cs < 4; cs++) {
            const float* sp = spart + (size_t)((cs * Bz + b) * Pz + p) * Kz + k0;
            float4 s0 = *(const float4*)sp;
            float4 s1 = *(const float4*)(sp + 4);
            q0.x += s0.x; q0.y += s0.y; q0.z += s0.z; q0.w += s0.w;
            q1.x += s1.x; q1.y += s1.y; q1.z += s1.z; q1.w += s1.w;
        }
        float4 w0 = *(const float4*)(W_i + k0);
        float4 w1 = *(const float4*)(W_i + k0 + 4);
        float acc = tanhf(q0.x) * w0.x + tanhf(q0.y) * w0.y
                  + tanhf(q0.z) * w0.z + tanhf(q0.w) * w0.w
                  + tanhf(q1.x) * w1.x + tanhf(q1.y) * w1.y
                  + tanhf(q1.z) * w1.z + tanhf(q1.w) * w1.w;
        acc = waveReduce(acc);
        if (lane == 0) sL[b] = acc + b_i[0];
        __syncthreads();
        if (tid < 8) {
            float m = -1e30f;
            #pragma unroll
            for (int j = 0; j < 8; j++) m = fmaxf(m, sL[j]);
            float s = 0.0f;
            #pragma unroll
            for (int j = 0; j < 8; j++) s += expf(sL[j] - m);
            alpha[tid * Pz + p] = expf(sL[tid] - m) / s;
        }
    } else if (t > 0) {
        int gw2 = (blk - 64) * 8 + wave;
        predsWave(h, wb, b_fc, out, t - 1, 9872 + gw2 * 4, lane);
    }
}

// ---- k5: awe -> xcat | emb/h fill | preds ----
__global__ __launch_bounds__(256) void k5(
    const float* __restrict__ enc, const float* __restrict__ beta,
    const float* __restrict__ alpha, const float* __restrict__ emb,
    const int* __restrict__ caps, const float* __restrict__ h,
    const unsigned short* __restrict__ wb, const float* __restrict__ b_fc,
    float* __restrict__ xcat, float* __restrict__ out, int t) {
    int blk = blockIdx.x, tid = threadIdx.x;
    int wave = tid >> 6, lane = tid & 63;
    if (blk < 4096) {
        int w = blk * 4 + wave;
        int b = w >> 11, c = w & 2047;
        float al = alpha[b * Pz + lane];
        float v = enc[(size_t)w * 64 + lane] * al;
        v = waveReduce(v);
        if (lane == 0) xcat[b * 3072 + Ez + c] = beta[w] * v * (1.0f / 64.0f);
    } else if (blk < 4128) {
        int idx = (blk - 4096) * 256 + tid;
        int b = idx >> 10, r = idx & 1023;
        if (r < Ez) xcat[b * 3072 + r] = emb[(size_t)caps[b * T1z + t] * Ez + r];
        else        xcat[b * 3072 + 2560 + (r - Ez)] = h[b * Dz + (r - Ez)];
    } else if (t > 0) {
        int gw2 = (blk - 4128) * 4 + wave;
        predsWave(h, wb, b_fc, out, t - 1, 14928 + gw2 * 4, lane);
    }
}

// ---- k6: gates + cell fused (block = one d; 4 waves = 4 gates; lanes = (b,e8)) ----
__global__ __launch_bounds__(256) void k6(
    const float* __restrict__ xcat, const unsigned short* __restrict__ wb,
    const float* __restrict__ b_ih, const float* __restrict__ b_hh,
    float* __restrict__ h, float* __restrict__ c) {
    __shared__ float sred[32];
    int d = blockIdx.x, tid = threadIdx.x;
    int wave = tid >> 6, lane = tid & 63;
    int bb = lane >> 3, e8 = lane & 7;
    int j = wave * 512 + d;
    const uint4* Wih4 = (const uint4*)(wb + O_WIH + (size_t)j * 2560);
    const uint4* Whh4 = (const uint4*)(wb + O_WHH + (size_t)j * 512);
    const float* xb = xcat + bb * 3072;
    float acc = 0.0f;
    #pragma unroll 4
    for (int i = 0; i < 48; i++) {
        int e0 = i * 64 + e8 * 8;
        uint4 w = (i < 40) ? Wih4[i * 8 + e8] : Whh4[(i - 40) * 8 + e8];
        float4 x0 = *(const float4*)(xb + e0);
        float4 x1 = *(const float4*)(xb + e0 + 4);
        acc = fmaf(x0.x, bLO(w.x), acc); acc = fmaf(x0.y, bHI(w.x), acc);
        acc = fmaf(x0.z, bLO(w.y), acc); acc = fmaf(x0.w, bHI(w.y), acc);
        acc = fmaf(x1.x, bLO(w.z), acc); acc = fmaf(x1.y, bHI(w.z), acc);
        acc = fmaf(x1.z, bLO(w.w), acc); acc = fmaf(x1.w, bHI(w.w), acc);
    }
    acc += __shfl_xor(acc, 1);
    acc += __shfl_xor(acc, 2);
    acc += __shfl_xor(acc, 4);
    if (e8 == 0) sred[wave * 8 + bb] = acc;
    __syncthreads();
    if (tid < 8) {
        int b = tid;
        float gI = sred[b]      + b_ih[d]        + b_hh[d];
        float gF = sred[8 + b]  + b_ih[512 + d]  + b_hh[512 + d];
        float gG = sred[16 + b] + b_ih[1024 + d] + b_hh[1024 + d];
        float gO = sred[24 + b] + b_ih[1536 + d] + b_hh[1536 + d];
        float ig = sigf(gI), fg = sigf(gF), gt = tanhf(gG), og = sigf(gO);
        int idx = b * Dz + d;
        float cn = fg * c[idx] + ig * gt;
        c[idx] = cn;
        h[idx] = og * tanhf(cn);
    }
}

// ---- final preds for t = 11 ----
__global__ __launch_bounds__(256) void k_predsF(
    const float* __restrict__ h, const unsigned short* __restrict__ wb,
    const float* __restrict__ b_fc, float* __restrict__ out) {
    int gw = blockIdx.x * 4 + (threadIdx.x >> 6);
    predsWave(h, wb, b_fc, out, Tz - 1, gw * 4, threadIdx.x & 63);
}

extern "C" void kernel_launch(void* const* d_in, const int* in_sizes, int n_in,
                              void* d_out, int out_size, void* d_ws, size_t ws_size,
                              hipStream_t stream) {
    const float* enc      = (const float*)d_in[0];
    const int*   caps     = (const int*)d_in[1];
    const int*   caplen   = (const int*)d_in[2];
    const float* W_c      = (const float*)d_in[3];
    const float* W_hc     = (const float*)d_in[4];
    const float* W_i_hat  = (const float*)d_in[5];
    const float* b_c      = (const float*)d_in[6];
    const float* b_i_hat  = (const float*)d_in[7];
    const float* W_s      = (const float*)d_in[8];
    const float* W_hs     = (const float*)d_in[9];
    const float* W_i      = (const float*)d_in[10];
    const float* b_s      = (const float*)d_in[11];
    const float* b_i      = (const float*)d_in[12];
    const float* emb      = (const float*)d_in[13];
    const float* W_ih     = (const float*)d_in[14];
    const float* W_hh     = (const float*)d_in[15];
    const float* b_ih     = (const float*)d_in[16];
    const float* b_hh     = (const float*)d_in[17];
    const float* W_init_h = (const float*)d_in[18];
    const float* b_init_h = (const float*)d_in[19];
    const float* W_init_c = (const float*)d_in[20];
    const float* b_init_c = (const float*)d_in[21];
    const float* W_fc     = (const float*)d_in[22];
    const float* b_fc     = (const float*)d_in[23];
    (void)b_i_hat;
    float* out = (float*)d_out;
    float* ws  = (float*)d_ws;

    float* vmean = ws;                       // 16384
    float* h     = ws + 16384;               // 4096
    float* c     = ws + 20480;               // 4096
    float* qc    = ws + 24576;               // 4096
    float* qs    = ws + 28672;               // 4096
    float* beta  = ws + 32768;               // 16384
    float* alpha = ws + 49152;               // 512
    float* xcat  = ws + 49664;               // 24576
    float* spart = ws + 74240;               // 4*8*64*512 = 1048576
    unsigned short* abf = (unsigned short*)(ws + 1122816);   // 1048576 ushorts
    unsigned short* wb  = (unsigned short*)(ws + 1647104);   // 18104320 ushorts

    k_prep<<<4353, 256, 0, stream>>>(W_fc, W_ih, W_hh, W_s, W_hc, W_hs,
                                     enc, caps, caplen, wb, vmean, out);
    k_init<<<256, 256, 0, stream>>>(vmean, W_init_h, b_init_h, W_init_c, b_init_c, h, c);
    for (int t = 0; t < Tz; t++) {
        k_binit<<<32, 256, 0, stream>>>(b_c, b_s, qc, qs);
        k1<<<316, 256, 0, stream>>>(h, wb, b_c, b_s, b_fc, qc, qs, out, t);
        k2<<<256, 256, 0, stream>>>(vmean, W_c, qc, W_i_hat, enc, beta, abf);
        k3<<<573, 256, 0, stream>>>(abf, wb, h, b_fc, spart, out, t);
        k4<<<222, 512, 0, stream>>>(spart, qs, W_i, b_i, h, wb, b_fc, alpha, out, t);
        k5<<<4445, 256, 0, stream>>>(enc, beta, alpha, emb, caps, h, wb, b_fc,
                                     xcat, out, t);
        k6<<<512, 256, 0, stream>>>(xcat, wb, b_ih, b_hh, h, c);
    }
    k_predsF<<<1250, 256, 0, stream>>>(h, wb, b_fc, out);
}